// Round 1
// baseline (4208.141 us; speedup 1.0000x reference)
//
#include <hip/hip_runtime.h>
#include <math.h>

// ---------------- degree / normalization ----------------

__global__ void deg_init_k(float* __restrict__ deg, int n) {
    int i = blockIdx.x * blockDim.x + threadIdx.x;
    if (i < n) deg[i] = 1.0f;  // self-loop contributes 1
}

__global__ void deg_count_k(const int* __restrict__ dst, float* __restrict__ deg, int E) {
    int e = blockIdx.x * blockDim.x + threadIdx.x;
    if (e < E) atomicAdd(&deg[dst[e]], 1.0f);
}

__global__ void dinv_k(float* __restrict__ deg, int n) {
    int i = blockIdx.x * blockDim.x + threadIdx.x;
    if (i < n) {
        float d = deg[i];
        deg[i] = 1.0f / sqrtf(d);  // deg >= 1 always (self-loop)
    }
}

// ---------------- dense GEMMs (fp32 vector ALU; no fp32 MFMA on CDNA4) ----------------

// h[n,128] = x[n,256] @ W[256,128]; 8 rows per block, 128 threads (1 col each)
__global__ void gemm1_k(const float* __restrict__ x, const float* __restrict__ W,
                        float* __restrict__ h, int n) {
    int r0 = blockIdx.x * 8;
    int t = threadIdx.x;  // 0..127 -> output column
    __shared__ float xs[8][256];
    for (int i = t; i < 8 * 256; i += 128) {
        int r = i >> 8, k = i & 255;
        int row = r0 + r;
        xs[r][k] = (row < n) ? x[(long long)row * 256 + k] : 0.0f;
    }
    __syncthreads();
    float acc[8] = {0, 0, 0, 0, 0, 0, 0, 0};
#pragma unroll 4
    for (int k = 0; k < 256; ++k) {
        float w = W[k * 128 + t];
#pragma unroll
        for (int r = 0; r < 8; ++r) acc[r] += xs[r][k] * w;
    }
#pragma unroll
    for (int r = 0; r < 8; ++r) {
        int row = r0 + r;
        if (row < n) h[(long long)row * 128 + t] = acc[r];
    }
}

// h2[n,64] = h1[n,128] @ W[128,64]; 8 rows per block, 64 threads
__global__ void gemm2_k(const float* __restrict__ h1, const float* __restrict__ W,
                        float* __restrict__ h2, int n) {
    int r0 = blockIdx.x * 8;
    int t = threadIdx.x;  // 0..63 -> output column
    __shared__ float xs[8][128];
    for (int i = t; i < 8 * 128; i += 64) {
        int r = i >> 7, k = i & 127;
        int row = r0 + r;
        xs[r][k] = (row < n) ? h1[(long long)row * 128 + k] : 0.0f;
    }
    __syncthreads();
    float acc[8] = {0, 0, 0, 0, 0, 0, 0, 0};
#pragma unroll 4
    for (int k = 0; k < 128; ++k) {
        float w = W[k * 64 + t];
#pragma unroll
        for (int r = 0; r < 8; ++r) acc[r] += xs[r][k] * w;
    }
#pragma unroll
    for (int r = 0; r < 8; ++r) {
        int row = r0 + r;
        if (row < n) h2[(long long)row * 64 + t] = acc[r];
    }
}

// ---------------- aggregation ----------------

// agg[i,c] = dinv[i]^2 * h[i,c]   (self-loop term, also zero-initializes)
template <int LOG2C>
__global__ void self_init_k(const float* __restrict__ h, const float* __restrict__ dinv,
                            float* __restrict__ agg, long long total) {
    long long id = (long long)blockIdx.x * blockDim.x + threadIdx.x;
    if (id < total) {
        int i = (int)(id >> LOG2C);
        float di = dinv[i];
        agg[id] = di * di * h[id];
    }
}

// edge scatter: C channels, C/4 lanes per edge, float4 gather + scalar atomics
template <int C>
__global__ void agg_edge_k(const int* __restrict__ src, const int* __restrict__ dst,
                           const float* __restrict__ dinv, const float* __restrict__ h,
                           float* __restrict__ agg, int E) {
    constexpr int LPE = C / 4;
    long long gid = (long long)blockIdx.x * blockDim.x + threadIdx.x;
    long long e = gid / LPE;
    int lane = (int)(gid % LPE);
    if (e >= E) return;
    int s = src[e], d = dst[e];
    float nrm = dinv[s] * dinv[d];
    const float4* hp = (const float4*)(h + (long long)s * C);
    float4 v = hp[lane];
    float* o = agg + (long long)d * C + lane * 4;
    atomicAdd(o + 0, nrm * v.x);
    atomicAdd(o + 1, nrm * v.y);
    atomicAdd(o + 2, nrm * v.z);
    atomicAdd(o + 3, nrm * v.w);
}

// h1 = relu(agg + b1), in place; C=128
__global__ void bias_relu_k(float* __restrict__ a, const float* __restrict__ b, long long total) {
    long long id = (long long)blockIdx.x * blockDim.x + threadIdx.x;
    if (id < total) {
        float v = a[id] + b[id & 127];
        a[id] = v > 0.0f ? v : 0.0f;
    }
}

// out[0:n*64) = predictions, out[n*64:2*n*64) = probabilities
__global__ void finalize_k(const float* __restrict__ agg2, const float* __restrict__ b2,
                           float* __restrict__ out, long long total) {
    long long id = (long long)blockIdx.x * blockDim.x + threadIdx.x;
    if (id < total) {
        float logit = agg2[id] + b2[id & 63];
        float p = 1.0f / (1.0f + expf(-logit));
        out[id] = (p > 0.5f) ? 1.0f : 0.0f;
        out[total + id] = p;
    }
}

// ---------------- launch ----------------

extern "C" void kernel_launch(void* const* d_in, const int* in_sizes, int n_in,
                              void* d_out, int out_size, void* d_ws, size_t ws_size,
                              hipStream_t stream) {
    const float* x  = (const float*)d_in[0];
    const int*   ei = (const int*)d_in[1];
    const float* W1 = (const float*)d_in[2];
    const float* b1 = (const float*)d_in[3];
    const float* W2 = (const float*)d_in[4];
    const float* b2 = (const float*)d_in[5];
    float* out = (float*)d_out;

    const int n = in_sizes[0] / 256;   // 50000
    const int E = in_sizes[1] / 2;     // 1.6M
    const int* src = ei;
    const int* dst = ei + E;

    float* ws   = (float*)d_ws;
    float* dinv = ws;                       // n floats (deg -> dinv in place)
    float* h0   = ws + n;                   // n*128
    float* agg1 = h0 + (long long)n * 128;  // n*128 (becomes h1 after bias+relu)
    float* h2   = agg1 + (long long)n * 128;// n*64
    float* agg2 = h2 + (long long)n * 64;   // n*64

    const long long t1 = (long long)n * 128;
    const long long t2 = (long long)n * 64;

    deg_init_k<<<(n + 255) / 256, 256, 0, stream>>>(dinv, n);
    deg_count_k<<<(E + 255) / 256, 256, 0, stream>>>(dst, dinv, E);
    dinv_k<<<(n + 255) / 256, 256, 0, stream>>>(dinv, n);

    gemm1_k<<<(n + 7) / 8, 128, 0, stream>>>(x, W1, h0, n);

    self_init_k<7><<<(int)((t1 + 255) / 256), 256, 0, stream>>>(h0, dinv, agg1, t1);
    {
        long long threads = (long long)E * 32;
        agg_edge_k<128><<<(int)((threads + 255) / 256), 256, 0, stream>>>(src, dst, dinv, h0, agg1, E);
    }
    bias_relu_k<<<(int)((t1 + 255) / 256), 256, 0, stream>>>(agg1, b1, t1);

    gemm2_k<<<(n + 7) / 8, 64, 0, stream>>>(agg1, W2, h2, n);

    self_init_k<6><<<(int)((t2 + 255) / 256), 256, 0, stream>>>(h2, dinv, agg2, t2);
    {
        long long threads = (long long)E * 16;
        agg_edge_k<64><<<(int)((threads + 255) / 256), 256, 0, stream>>>(src, dst, dinv, h2, agg2, E);
    }
    finalize_k<<<(int)((t2 + 255) / 256), 256, 0, stream>>>(agg2, b2, out, t2);
}

// Round 2
// 446.128 us; speedup vs baseline: 9.4326x; 9.4326x over previous
//
#include <hip/hip_runtime.h>
#include <math.h>

// ================= CSR build =================

__global__ void deg_count_k(const int* __restrict__ dst, int* __restrict__ cnt, int E) {
    int e = blockIdx.x * blockDim.x + threadIdx.x;
    if (e < E) atomicAdd(&cnt[dst[e]], 1);
}

// per-block exclusive scan of cnt -> row_off (local), block totals -> bsum
__global__ void scan_local_k(const int* __restrict__ cnt, int* __restrict__ row_off,
                             int* __restrict__ bsum, int n) {
    __shared__ int tmp[256];
    int t = threadIdx.x;
    int i = blockIdx.x * 256 + t;
    int v = (i < n) ? cnt[i] : 0;
    tmp[t] = v;
    __syncthreads();
    for (int off = 1; off < 256; off <<= 1) {
        int a = (t >= off) ? tmp[t - off] : 0;
        __syncthreads();
        tmp[t] += a;
        __syncthreads();
    }
    if (i < n) row_off[i] = tmp[t] - v;  // exclusive
    if (t == 255) bsum[blockIdx.x] = tmp[255];
}

// single-block exclusive scan of bsum (nb <= 256)
__global__ void scan_block_k(int* __restrict__ bsum, int nb) {
    __shared__ int tmp[256];
    int t = threadIdx.x;
    int v = (t < nb) ? bsum[t] : 0;
    tmp[t] = v;
    __syncthreads();
    for (int off = 1; off < 256; off <<= 1) {
        int a = (t >= off) ? tmp[t - off] : 0;
        __syncthreads();
        tmp[t] += a;
        __syncthreads();
    }
    if (t < nb) bsum[t] = tmp[t] - v;
}

__global__ void scan_add_k(int* __restrict__ row_off, const int* __restrict__ bsum,
                           int n, int E) {
    int i = blockIdx.x * 256 + threadIdx.x;
    if (i < n) row_off[i] += bsum[blockIdx.x];
    if (i == 0) row_off[n] = E;
}

__global__ void dinv_k(const int* __restrict__ cnt, float* __restrict__ dinv, int n) {
    int i = blockIdx.x * blockDim.x + threadIdx.x;
    if (i < n) dinv[i] = rsqrtf((float)(cnt[i] + 1));  // +1 = self-loop
}

__global__ void fill_k(const int* __restrict__ src, const int* __restrict__ dst,
                       const int* __restrict__ row_off, int* __restrict__ fill,
                       int* __restrict__ csr, int E) {
    int e = blockIdx.x * blockDim.x + threadIdx.x;
    if (e < E) {
        int d = dst[e];
        int p = row_off[d] + atomicAdd(&fill[d], 1);
        csr[p] = src[e];
    }
}

// ================= dense GEMMs (fp32 vector ALU), dinv-scaled epilogue =================

// hs[n,128] = (x[n,256] @ W[256,128]) * dinv[row]
__global__ void gemm1_k(const float* __restrict__ x, const float* __restrict__ W,
                        const float* __restrict__ dinv, float* __restrict__ hs, int n) {
    int r0 = blockIdx.x * 8;
    int t = threadIdx.x;  // 0..127 -> output column
    __shared__ float xs[8][256];
    for (int i = t; i < 8 * 256; i += 128) {
        int r = i >> 8, k = i & 255;
        int row = r0 + r;
        xs[r][k] = (row < n) ? x[(long long)row * 256 + k] : 0.0f;
    }
    __syncthreads();
    float acc[8] = {0, 0, 0, 0, 0, 0, 0, 0};
#pragma unroll 4
    for (int k = 0; k < 256; ++k) {
        float w = W[k * 128 + t];
#pragma unroll
        for (int r = 0; r < 8; ++r) acc[r] += xs[r][k] * w;
    }
#pragma unroll
    for (int r = 0; r < 8; ++r) {
        int row = r0 + r;
        if (row < n) hs[(long long)row * 128 + t] = acc[r] * dinv[row];
    }
}

// hs2[n,64] = (h1[n,128] @ W[128,64]) * dinv[row]
__global__ void gemm2_k(const float* __restrict__ h1, const float* __restrict__ W,
                        const float* __restrict__ dinv, float* __restrict__ hs2, int n) {
    int r0 = blockIdx.x * 8;
    int t = threadIdx.x;  // 0..63 -> output column
    __shared__ float xs[8][128];
    for (int i = t; i < 8 * 128; i += 64) {
        int r = i >> 7, k = i & 127;
        int row = r0 + r;
        xs[r][k] = (row < n) ? h1[(long long)row * 128 + k] : 0.0f;
    }
    __syncthreads();
    float acc[8] = {0, 0, 0, 0, 0, 0, 0, 0};
#pragma unroll 4
    for (int k = 0; k < 128; ++k) {
        float w = W[k * 64 + t];
#pragma unroll
        for (int r = 0; r < 8; ++r) acc[r] += xs[r][k] * w;
    }
#pragma unroll
    for (int r = 0; r < 8; ++r) {
        int row = r0 + r;
        if (row < n) hs2[(long long)row * 64 + t] = acc[r] * dinv[row];
    }
}

// ================= gather-side aggregation (no atomics) =================

// h1[i] = relu(dinv[i]*(hs[i] + sum_{j in N(i)} hs[j]) + b1)   C=128, 32 lanes/node
__global__ void gather1_k(const float* __restrict__ hs, const int* __restrict__ row_off,
                          const int* __restrict__ csr, const float* __restrict__ dinv,
                          const float* __restrict__ b1, float* __restrict__ h1, int n) {
    int g = threadIdx.x >> 5;
    int lane = threadIdx.x & 31;
    int i = blockIdx.x * 8 + g;
    if (i >= n) return;
    float4 acc = ((const float4*)(hs + (long long)i * 128))[lane];  // self term
    int beg = row_off[i], end = row_off[i + 1];
    int j = beg;
    for (; j + 1 < end; j += 2) {
        int s0 = csr[j], s1 = csr[j + 1];
        float4 v0 = ((const float4*)(hs + (long long)s0 * 128))[lane];
        float4 v1 = ((const float4*)(hs + (long long)s1 * 128))[lane];
        acc.x += v0.x; acc.y += v0.y; acc.z += v0.z; acc.w += v0.w;
        acc.x += v1.x; acc.y += v1.y; acc.z += v1.z; acc.w += v1.w;
    }
    if (j < end) {
        int s0 = csr[j];
        float4 v0 = ((const float4*)(hs + (long long)s0 * 128))[lane];
        acc.x += v0.x; acc.y += v0.y; acc.z += v0.z; acc.w += v0.w;
    }
    float di = dinv[i];
    float4 bb = ((const float4*)b1)[lane];
    float4 o;
    o.x = fmaxf(di * acc.x + bb.x, 0.0f);
    o.y = fmaxf(di * acc.y + bb.y, 0.0f);
    o.z = fmaxf(di * acc.z + bb.z, 0.0f);
    o.w = fmaxf(di * acc.w + bb.w, 0.0f);
    ((float4*)(h1 + (long long)i * 128))[lane] = o;
}

// logits -> pred/prob, C=64, 16 lanes/node. out[0:t)=pred, out[t:2t)=prob
__global__ void gather2_k(const float* __restrict__ hs2, const int* __restrict__ row_off,
                          const int* __restrict__ csr, const float* __restrict__ dinv,
                          const float* __restrict__ b2, float* __restrict__ out, int n) {
    int g = threadIdx.x >> 4;
    int lane = threadIdx.x & 15;
    int i = blockIdx.x * 16 + g;
    if (i >= n) return;
    float4 acc = ((const float4*)(hs2 + (long long)i * 64))[lane];  // self term
    int beg = row_off[i], end = row_off[i + 1];
    int j = beg;
    for (; j + 1 < end; j += 2) {
        int s0 = csr[j], s1 = csr[j + 1];
        float4 v0 = ((const float4*)(hs2 + (long long)s0 * 64))[lane];
        float4 v1 = ((const float4*)(hs2 + (long long)s1 * 64))[lane];
        acc.x += v0.x; acc.y += v0.y; acc.z += v0.z; acc.w += v0.w;
        acc.x += v1.x; acc.y += v1.y; acc.z += v1.z; acc.w += v1.w;
    }
    if (j < end) {
        int s0 = csr[j];
        float4 v0 = ((const float4*)(hs2 + (long long)s0 * 64))[lane];
        acc.x += v0.x; acc.y += v0.y; acc.z += v0.z; acc.w += v0.w;
    }
    float di = dinv[i];
    float4 bb = ((const float4*)b2)[lane];
    float lx = di * acc.x + bb.x;
    float ly = di * acc.y + bb.y;
    float lz = di * acc.z + bb.z;
    float lw = di * acc.w + bb.w;
    float4 p;
    p.x = 1.0f / (1.0f + expf(-lx));
    p.y = 1.0f / (1.0f + expf(-ly));
    p.z = 1.0f / (1.0f + expf(-lz));
    p.w = 1.0f / (1.0f + expf(-lw));
    long long total = (long long)n * 64;
    long long o0 = (long long)i * 64 + lane * 4;
    float4 pr;
    pr.x = (p.x > 0.5f) ? 1.0f : 0.0f;
    pr.y = (p.y > 0.5f) ? 1.0f : 0.0f;
    pr.z = (p.z > 0.5f) ? 1.0f : 0.0f;
    pr.w = (p.w > 0.5f) ? 1.0f : 0.0f;
    *(float4*)(out + o0) = pr;
    *(float4*)(out + total + o0) = p;
}

// ================= launch =================

extern "C" void kernel_launch(void* const* d_in, const int* in_sizes, int n_in,
                              void* d_out, int out_size, void* d_ws, size_t ws_size,
                              hipStream_t stream) {
    const float* x  = (const float*)d_in[0];
    const int*   ei = (const int*)d_in[1];
    const float* W1 = (const float*)d_in[2];
    const float* b1 = (const float*)d_in[3];
    const float* W2 = (const float*)d_in[4];
    const float* b2 = (const float*)d_in[5];
    float* out = (float*)d_out;

    const int n = in_sizes[0] / 256;   // 50000
    const int E = in_sizes[1] / 2;     // 1.6M
    const int* src = ei;
    const int* dst = ei + E;

    // ---- workspace carve-up (256B-aligned) ----
    char* base = (char*)d_ws;
    size_t off = 0;
    auto carve = [&](size_t bytes) -> void* {
        void* p = base + off;
        off = (off + bytes + 255) & ~(size_t)255;
        return p;
    };
    int*   cntfill = (int*)  carve((size_t)2 * n * sizeof(int)); // cnt[n] then fill[n]
    int*   cnt  = cntfill;
    int*   fill = cntfill + n;
    int*   row_off = (int*)  carve((size_t)(n + 1) * sizeof(int));
    int*   bsum    = (int*)  carve(256 * sizeof(int));
    int*   csr     = (int*)  carve((size_t)E * sizeof(int));
    float* dinv    = (float*)carve((size_t)n * sizeof(float));
    float* hs0     = (float*)carve((size_t)n * 128 * sizeof(float));
    float* h1      = (float*)carve((size_t)n * 128 * sizeof(float));
    float* hs2     = (float*)carve((size_t)n * 64 * sizeof(float));

    const int nb = (n + 255) / 256;  // scan blocks (196)

    hipMemsetAsync(cntfill, 0, (size_t)2 * n * sizeof(int), stream);
    deg_count_k<<<(E + 255) / 256, 256, 0, stream>>>(dst, cnt, E);
    scan_local_k<<<nb, 256, 0, stream>>>(cnt, row_off, bsum, n);
    scan_block_k<<<1, 256, 0, stream>>>(bsum, nb);
    scan_add_k<<<nb, 256, 0, stream>>>(row_off, bsum, n, E);
    dinv_k<<<(n + 255) / 256, 256, 0, stream>>>(cnt, dinv, n);
    fill_k<<<(E + 255) / 256, 256, 0, stream>>>(src, dst, row_off, fill, csr, E);

    gemm1_k<<<(n + 7) / 8, 128, 0, stream>>>(x, W1, dinv, hs0, n);
    gather1_k<<<(n + 7) / 8, 256, 0, stream>>>(hs0, row_off, csr, dinv, b1, h1, n);
    gemm2_k<<<(n + 7) / 8, 64, 0, stream>>>(h1, W2, dinv, hs2, n);
    gather2_k<<<(n + 15) / 16, 256, 0, stream>>>(hs2, row_off, csr, dinv, b2, out, n);
}